// Round 12
// baseline (262.989 us; speedup 1.0000x reference)
//
#include <hip/hip_runtime.h>
#include <math.h>

constexpr int cE = 8;
constexpr int cH = 1024;
constexpr int cF = 2816;
constexpr int cR = 256;
constexpr int cT = 2048;
constexpr int ROWS = cT * 2;   // total routed (token, expert) rows = T*K
constexpr int LDA = 40;        // padded LDS row stride (foldm reg-staged kernel)

using short8  = __attribute__((ext_vector_type(8))) short;
using float4v = __attribute__((ext_vector_type(4))) float;
#define MFMA16 __builtin_amdgcn_mfma_f32_16x16x32_bf16

__device__ __forceinline__ unsigned short f2bf(float f) {
  union { float f; unsigned u; } v; v.f = f;
  unsigned r = v.u + 0x7fffu + ((v.u >> 16) & 1u);   // RNE
  return (unsigned short)(r >> 16);
}
__device__ __forceinline__ float bf2f(unsigned short s) {
  union { unsigned u; float f; } v; v.u = (unsigned)s << 16; return v.f;
}

// pack 8 fp32 -> 8 bf16, single 16B store
__device__ __forceinline__ void store_bf8(unsigned short* dst, float4 a, float4 b) {
  union { unsigned short u[8]; uint4 v; } t;
  t.u[0] = f2bf(a.x); t.u[1] = f2bf(a.y); t.u[2] = f2bf(a.z); t.u[3] = f2bf(a.w);
  t.u[4] = f2bf(b.x); t.u[5] = f2bf(b.y); t.u[6] = f2bf(b.z); t.u[7] = f2bf(b.w);
  *reinterpret_cast<uint4*>(dst) = t.v;
}

// async global->LDS, 16 B per lane. LDS dest = wave-uniform base + lane*16,
// global source address is per-lane (gather/swizzle-capable).
__device__ __forceinline__ void gld16(const unsigned short* g, unsigned short* l) {
  __builtin_amdgcn_global_load_lds(
      (const __attribute__((address_space(1))) void*)g,
      (__attribute__((address_space(3))) void*)l, 16, 0, 0);
}

// ---------------------------------------------------------------------------
// 64x64 transpose tile (fp32 -> bf16): in [P][Q] per batch -> out [Q][P].
// ---------------------------------------------------------------------------
__device__ __forceinline__ void tconv_tile64(
    const float* __restrict__ in, unsigned short* __restrict__ out,
    int P, int Q, int e, int bx, int by, int tid, float (*tile)[65])
{
  const long es = (long)P * Q;
  in += e * es; out += e * es;
  const int c0 = bx * 64, r0 = by * 64;
  const int r = tid >> 4, c4 = (tid & 15) * 4;
#pragma unroll
  for (int p = 0; p < 4; ++p) {
    float4 v = *reinterpret_cast<const float4*>(
        in + (long)(r0 + p * 16 + r) * Q + c0 + c4);
    tile[p * 16 + r][c4 + 0] = v.x; tile[p * 16 + r][c4 + 1] = v.y;
    tile[p * 16 + r][c4 + 2] = v.z; tile[p * 16 + r][c4 + 3] = v.w;
  }
  __syncthreads();
  const int cc = tid >> 4, rr4 = (tid & 15) * 4;
#pragma unroll
  for (int p = 0; p < 4; ++p) {
    ushort4 o;
    o.x = f2bf(tile[rr4 + 0][p * 16 + cc]);
    o.y = f2bf(tile[rr4 + 1][p * 16 + cc]);
    o.z = f2bf(tile[rr4 + 2][p * 16 + cc]);
    o.w = f2bf(tile[rr4 + 3][p * 16 + cc]);
    *reinterpret_cast<ushort4*>(out + (long)(c0 + p * 16 + cc) * P + r0 + rr4) = o;
  }
}

// ---------------------------------------------------------------------------
// LAUNCH 1: SMALL transposes (Cg/Cu/Vd, 544 tiles) + gating + x->bf16.
//  [0,16) Cg | [16,32) Cu | [32,544) Vd | [544,1056) gating
// ---------------------------------------------------------------------------
constexpr int P1_TCONV = 544;
constexpr int PREP1_BLOCKS = P1_TCONV + cT / 4;

__global__ __launch_bounds__(256) void k_prep1s(
    const float* __restrict__ Cg, unsigned short* __restrict__ CgT,
    const float* __restrict__ Cu, unsigned short* __restrict__ CuT,
    const float* __restrict__ Vd, unsigned short* __restrict__ VdT,
    const float* __restrict__ x, const float* __restrict__ gw,
    unsigned short* __restrict__ xb, int* __restrict__ et,
    float* __restrict__ wt)
{
  __shared__ float tile[64][65];
  int b = blockIdx.x;
  const int tid = threadIdx.x;
  if (b < P1_TCONV) {
    const float* in; unsigned short* out; int P, Q;
    if (b < 16)       { in = Cg; out = CgT; P = 256; Q = 256;  }
    else if (b < 32)  { b -= 16; in = Cu; out = CuT; P = 256; Q = 256;  }
    else              { b -= 32; in = Vd; out = VdT; P = 256; Q = 1024; }
    const int tpe = (P / 64) * (Q / 64);
    const int e = b / tpe, rem = b % tpe;
    const int bx = rem % (Q / 64), by = rem / (Q / 64);
    tconv_tile64(in, out, P, Q, e, bx, by, tid, tile);
    return;
  }
  // ---- gating path ----
  const int wid = tid >> 6, lane = tid & 63;
  const int t = (b - P1_TCONV) * 4 + wid;
  const float* xr = x + (long)t * cH + lane * 16;
  float4 v0 = *reinterpret_cast<const float4*>(xr);
  float4 v1 = *reinterpret_cast<const float4*>(xr + 4);
  float4 v2 = *reinterpret_cast<const float4*>(xr + 8);
  float4 v3 = *reinterpret_cast<const float4*>(xr + 12);
  store_bf8(xb + (long)t * cH + lane * 16, v0, v1);
  store_bf8(xb + (long)t * cH + lane * 16 + 8, v2, v3);
  float xv[16];
  *reinterpret_cast<float4*>(&xv[0])  = v0;
  *reinterpret_cast<float4*>(&xv[4])  = v1;
  *reinterpret_cast<float4*>(&xv[8])  = v2;
  *reinterpret_cast<float4*>(&xv[12]) = v3;
  const float* g = gw + (long)lane * 16 * cE;
  float l[cE];
#pragma unroll
  for (int e = 0; e < cE; ++e) l[e] = 0.f;
#pragma unroll
  for (int i = 0; i < 16; ++i) {
    float4 ga = *reinterpret_cast<const float4*>(g + i * cE);
    float4 gb = *reinterpret_cast<const float4*>(g + i * cE + 4);
    float xi = xv[i];
    l[0] += xi * ga.x; l[1] += xi * ga.y; l[2] += xi * ga.z; l[3] += xi * ga.w;
    l[4] += xi * gb.x; l[5] += xi * gb.y; l[6] += xi * gb.z; l[7] += xi * gb.w;
  }
#pragma unroll
  for (int m = 1; m < 64; m <<= 1)
#pragma unroll
    for (int e = 0; e < cE; ++e)
      l[e] += __shfl_xor(l[e], m, 64);
  if (lane == 0) {
    int i0 = 0; float m0 = l[0];
#pragma unroll
    for (int e = 1; e < cE; ++e) if (l[e] > m0) { m0 = l[e]; i0 = e; }
    int i1 = -1; float m1 = -1e30f;
#pragma unroll
    for (int e = 0; e < cE; ++e) if (e != i0 && l[e] > m1) { m1 = l[e]; i1 = e; }
    float w0 = 1.f / (1.f + expf(m1 - m0));
    et[t * 2 + 0] = i0;  et[t * 2 + 1] = i1;
    wt[t * 2 + 0] = w0;  wt[t * 2 + 1] = 1.f - w0;
  }
}

// ---------------------------------------------------------------------------
// MFMA fold body: D[m][n] = sum_k A[m][k] * B[n][k],  K = 256 fixed.
// tile 128x64, BK=32, register prefetch.
// ---------------------------------------------------------------------------
__device__ __forceinline__ void foldm_body(
    const unsigned short* __restrict__ A, const float* __restrict__ B,
    unsigned short* __restrict__ D, int ldd, int m0, int n0, int tid,
    unsigned short* As, unsigned short* Bs)
{
  const int sr = tid >> 2, sk = (tid & 3) * 8;
  const unsigned short* a0 = A + (long)(m0 + sr) * 256 + sk;
  const unsigned short* a1 = a0 + (long)64 * 256;
  const float* br = B + (long)(n0 + sr) * 256 + sk;
  uint4 rA0, rA1; float4 rB0, rB1;
  auto load_slice = [&](int k0) {
    rA0 = *reinterpret_cast<const uint4*>(a0 + k0);
    rA1 = *reinterpret_cast<const uint4*>(a1 + k0);
    rB0 = *reinterpret_cast<const float4*>(br + k0);
    rB1 = *reinterpret_cast<const float4*>(br + k0 + 4);
  };
  load_slice(0);
  const int wid = tid >> 6, lane = tid & 63;
  const int wm = (wid >> 1) * 64, wn = (wid & 1) * 32;
  const int fr = lane & 15, fq = lane >> 4;
  float4v zf = {0.f, 0.f, 0.f, 0.f};
  float4v acc[4][2];
#pragma unroll
  for (int i = 0; i < 4; ++i) { acc[i][0] = zf; acc[i][1] = zf; }
  for (int k0 = 0; k0 < 256; k0 += 32) {
    *reinterpret_cast<uint4*>(&As[sr * LDA + sk]) = rA0;
    *reinterpret_cast<uint4*>(&As[(sr + 64) * LDA + sk]) = rA1;
    store_bf8(&Bs[sr * LDA + sk], rB0, rB1);
    if (k0 + 32 < 256) load_slice(k0 + 32);
    __syncthreads();
    short8 af[4], bf[2];
#pragma unroll
    for (int mi = 0; mi < 4; ++mi)
      af[mi] = *reinterpret_cast<const short8*>(&As[(wm + mi * 16 + fr) * LDA + fq * 8]);
#pragma unroll
    for (int nj = 0; nj < 2; ++nj)
      bf[nj] = *reinterpret_cast<const short8*>(&Bs[(wn + nj * 16 + fr) * LDA + fq * 8]);
#pragma unroll
    for (int mi = 0; mi < 4; ++mi)
#pragma unroll
      for (int nj = 0; nj < 2; ++nj)
        acc[mi][nj] = MFMA16(af[mi], bf[nj], acc[mi][nj], 0, 0, 0);
    __syncthreads();
  }
#pragma unroll
  for (int mi = 0; mi < 4; ++mi)
#pragma unroll
    for (int r = 0; r < 4; ++r) {
      int m = m0 + wm + mi * 16 + fq * 4 + r;
#pragma unroll
      for (int nj = 0; nj < 2; ++nj)
        D[(long)m * ldd + n0 + wn + nj * 16 + fr] = f2bf(acc[mi][nj][r]);
    }
}

// ---------------------------------------------------------------------------
// LAUNCH 2: folds (768) + lists (1) + BIG transposes Vg/Vu/Ud (4224 tiles).
//  [0,512) b1t folds | [512,768) vd2t folds | 768 lists |
//  [769,2177) Vg | [2177,3585) Vu | [3585,4993) Ud
// ---------------------------------------------------------------------------
constexpr int PREP2_BLOCKS = 769 + 3 * 1408;
__global__ __launch_bounds__(256, 3) void k_prep2(
    const unsigned short* __restrict__ CgT, const unsigned short* __restrict__ CuT,
    const float* __restrict__ Ug, const float* __restrict__ Uu,
    unsigned short* __restrict__ b1t,
    const unsigned short* __restrict__ VdT, const float* __restrict__ Cd,
    unsigned short* __restrict__ vd2t,
    const float* __restrict__ Vg, unsigned short* __restrict__ vgT,
    const float* __restrict__ Vu, unsigned short* __restrict__ vuT,
    const float* __restrict__ Ud, unsigned short* __restrict__ udT,
    const int* __restrict__ et, int* __restrict__ rowmap,
    int* __restrict__ tok, int* __restrict__ cnt, int* __restrict__ off)
{
  __shared__ __align__(16) char smem[64 * 65 * 4];   // 16640 B union
  const int b = blockIdx.x;
  const int tid = threadIdx.x;
  if (b < 512) {
    unsigned short* As = (unsigned short*)smem;
    unsigned short* Bs = As + 128 * LDA;
    const int bx = b & 15, by = (b >> 4) & 1, z = b >> 5;
    const int sel = z >> 3, e = z & 7;
    const unsigned short* A = sel ? CuT : CgT;
    const float* B = (sel ? Uu : Ug) + (long)e * cH * cR;
    unsigned short* Dp = b1t + (long)e * 512 * 1024 + (long)sel * 256 * 1024;
    foldm_body(A, B, Dp, cH, by * 128, bx * 64, tid, As, Bs);
  } else if (b < 768) {
    unsigned short* As = (unsigned short*)smem;
    unsigned short* Bs = As + 128 * LDA;
    const int b2 = b - 512;
    const int bx = b2 & 3, by = (b2 >> 2) & 7, e = b2 >> 5;
    foldm_body(VdT + (long)e * cH * cR, Cd, vd2t + (long)e * cH * 256, cR,
               by * 128, bx * 64, tid, As, Bs);
  } else if (b == 768) {
    // ---- lists path (single block) ----
    int* sc_ = (int*)smem;
    int* sp_ = sc_ + cE;
    int* so_ = sc_ + 2 * cE;
    if (tid < cE) { sc_[tid] = 0; sp_[tid] = 0; }
    __syncthreads();
    for (int i = tid; i < ROWS; i += 256) atomicAdd(&sc_[et[i]], 1);
    __syncthreads();
    if (tid == 0) {
      int s = 0;
      for (int e = 0; e < cE; ++e) { so_[e] = s; s += sc_[e]; }
    }
    __syncthreads();
    for (int i = tid; i < ROWS; i += 256) {
      int e = et[i];
      int slot = atomicAdd(&sp_[e], 1);
      int cr = so_[e] + slot;
      rowmap[i] = cr;
      tok[cr] = i >> 1;
    }
    if (tid < cE) { cnt[tid] = sc_[tid]; off[tid] = so_[tid]; }
  } else {
    // ---- big transpose path ----
    float (*tile)[65] = reinterpret_cast<float(*)[65]>(smem);
    int t = b - 769;
    const float* in; unsigned short* out; int P, Q;
    if (t < 1408)       { in = Vg; out = vgT; P = 256;  Q = 2816; }
    else if (t < 2816)  { t -= 1408; in = Vu; out = vuT; P = 256;  Q = 2816; }
    else                { t -= 2816; in = Ud; out = udT; P = 2816; Q = 256;  }
    const int tpe = (P / 64) * (Q / 64);
    const int e = t / tpe, rem = t % tpe;
    const int bx = rem % (Q / 64), by = rem / (Q / 64);
    tconv_tile64(in, out, P, Q, e, bx, by, tid, tile);
  }
}

// ---------------------------------------------------------------------------
// COMPACT t1 GEMM: t1[o+row] = xb[tok[o+row]] @ b1t[e]^T   (K=1024, N=512)
// M-TILE 64: tile 64x64, BK=64, acc[2][2], dbuf + XOR swizzle (8-chunk).
// grid = (8, cT/64, E), early-return past cnt[e].
// ---------------------------------------------------------------------------
__global__ __launch_bounds__(256, 4) void k_t1c(
    const unsigned short* __restrict__ xb, const unsigned short* __restrict__ b1t,
    unsigned short* __restrict__ t1, const int* __restrict__ tok,
    const int* __restrict__ cnt, const int* __restrict__ off)
{
  __shared__ __align__(16) unsigned short As[2][64 * 64], Bs[2][64 * 64];
  const int e = blockIdx.z, c = cnt[e], o = off[e];
  const int m0 = blockIdx.y * 64;
  if (m0 >= c) return;
  const int n0 = blockIdx.x * 64;
  const int tid = threadIdx.x;
  const int wid = tid >> 6, lane = tid & 63;
  const int sr8 = lane >> 3;
  const int scs = ((lane & 7) ^ sr8) * 8;          // pre-swizzled source col
  const unsigned short* gA[2];
#pragma unroll
  for (int j = 0; j < 2; ++j) {
    int row = min(m0 + wid * 16 + j * 8 + sr8, c - 1);
    gA[j] = xb + (long)tok[o + row] * cH + scs;
  }
  const unsigned short* gB = b1t + (long)e * 512 * 1024 +
      (long)(n0 + wid * 16 + sr8) * 1024 + scs;
  const int lofs = wid * 16 * 64;
  auto STAGE = [&](int k0, int buf) {
    gld16(gA[0] + k0, &As[buf][lofs]);
    gld16(gA[1] + k0, &As[buf][lofs + 8 * 64]);
    gld16(gB + k0, &Bs[buf][lofs]);
    gld16(gB + (long)8 * 1024 + k0, &Bs[buf][lofs + 8 * 64]);
  };
  const int wm = (wid >> 1) * 32, wn = (wid & 1) * 32;
  const int fr = lane & 15, fq = lane >> 4;
  const int swz = (fr & 7) * 8;                    // read-side XOR (shorts)
  float4v zf = {0.f, 0.f, 0.f, 0.f};
  float4v acc[2][2] = {{zf, zf}, {zf, zf}};
  STAGE(0, 0);
  __syncthreads();
  for (int t = 0; t < 16; ++t) {
    const int cur = t & 1;
    if (t < 15) STAGE((t + 1) * 64, cur ^ 1);
#pragma unroll
    for (int ks = 0; ks < 2; ++ks) {
      short8 af[2], bf[2];
#pragma unroll
      for (int mi = 0; mi < 2; ++mi)
        af[mi] = *reinterpret_cast<const short8*>(
            &As[cur][(wm + mi * 16 + fr) * 64 + ((ks * 32 + fq * 8) ^ swz)]);
#pragma unroll
      for (int nj = 0; nj < 2; ++nj)
        bf[nj] = *reinterpret_cast<const short8*>(
            &Bs[cur][(wn + nj * 16 + fr) * 64 + ((ks * 32 + fq * 8) ^ swz)]);
#pragma unroll
      for (int mi = 0; mi < 2; ++mi)
#pragma unroll
        for (int nj = 0; nj < 2; ++nj)
          acc[mi][nj] = MFMA16(af[mi], bf[nj], acc[mi][nj], 0, 0, 0);
    }
    __syncthreads();
  }
#pragma unroll
  for (int mi = 0; mi < 2; ++mi)
#pragma unroll
    for (int r = 0; r < 4; ++r) {
      int row = m0 + wm + mi * 16 + fq * 4 + r;
      if (row < c) {
#pragma unroll
        for (int nj = 0; nj < 2; ++nj)
          t1[(long)(o + row) * 512 + n0 + wn + nj * 16 + fr] = f2bf(acc[mi][nj][r]);
      }
    }
}

// ---------------------------------------------------------------------------
// dual GEMM: a = silu(t1g @ vgT^T) * (t1u @ vuT^T)  [rows x F], K=256
// WIDE RETILE: block 64x128, wave acc 2x4 (12 LDS reads feed 16 MFMA,
// 0.75 reads/MFMA vs 1.0 before; A restaged 22x not 44x). BK=32, dbuf,
// LDS 48 KB -> 3 blocks/CU. XOR swizzle (4-chunk). grid = (22, cT/64, E)
// ---------------------------------------------------------------------------
__global__ __launch_bounds__(256, 3) void k_act(
    const unsigned short* __restrict__ t1,
    const unsigned short* __restrict__ vgT, const unsigned short* __restrict__ vuT,
    unsigned short* __restrict__ a, const int* __restrict__ cnt,
    const int* __restrict__ off)
{
  __shared__ __align__(16) unsigned short Ag[2][64 * 32], Au[2][64 * 32];
  __shared__ __align__(16) unsigned short Bg[2][128 * 32], Bu[2][128 * 32];
  const int e = blockIdx.z, c = cnt[e], o = off[e];
  const int m0 = blockIdx.y * 64;
  if (m0 >= c) return;
  const int n0 = blockIdx.x * 128;
  const int tid = threadIdx.x;
  const int wid = tid >> 6, lane = tid & 63;
  const int sr16 = lane >> 2;                       // 0..15
  const int scs = (((lane & 3) ^ (sr16 & 3)) * 8);  // 4-chunk involution
  // A: 64 rows; wave stages 16 rows (g half at +0, u half at +256)
  const int ra = o + min(m0 + wid * 16 + sr16, c - 1);
  const unsigned short* gA = t1 + (long)ra * 512 + scs;
  // B: 128 rows; wave stages 32 rows (two gld16 per matrix)
  const unsigned short* gBg0 = vgT + (long)e * cF * 256 +
      (long)(n0 + wid * 32 + sr16) * 256 + scs;
  const unsigned short* gBg1 = gBg0 + (long)16 * 256;
  const unsigned short* gBu0 = vuT + (long)e * cF * 256 +
      (long)(n0 + wid * 32 + sr16) * 256 + scs;
  const unsigned short* gBu1 = gBu0 + (long)16 * 256;
  const int lA = wid * 16 * 32;      // 16 rows x 32 shorts
  const int lB = wid * 32 * 32;      // 32 rows x 32 shorts
  auto STAGE = [&](int k0, int buf) {
    gld16(gA + k0,        &Ag[buf][lA]);
    gld16(gA + 256 + k0,  &Au[buf][lA]);
    gld16(gBg0 + k0,      &Bg[buf][lB]);
    gld16(gBg1 + k0,      &Bg[buf][lB + 16 * 32]);
    gld16(gBu0 + k0,      &Bu[buf][lB]);
    gld16(gBu1 + k0,      &Bu[buf][lB + 16 * 32]);
  };
  const int wm = (wid >> 1) * 32, wn = (wid & 1) * 64;  // 2x2 wave grid / 64x128
  const int fr = lane & 15, fq = lane >> 4;
  const int swz = (fr & 3) * 8;                    // read-side XOR (shorts)
  float4v zf = {0.f, 0.f, 0.f, 0.f};
  float4v accg[2][4], accu[2][4];
#pragma unroll
  for (int i = 0; i < 2; ++i)
#pragma unroll
    for (int j = 0; j < 4; ++j) { accg[i][j] = zf; accu[i][j] = zf; }
  STAGE(0, 0);
  __syncthreads();
  for (int t = 0; t < 8; ++t) {
    const int cur = t & 1;
    if (t < 7) STAGE((t + 1) * 32, cur ^ 1);
    short8 ag[2], au[2], bg[4], bu[4];
#pragma unroll
    for (int mi = 0; mi < 2; ++mi) {
      ag[mi] = *reinterpret_cast<const short8*>(
          &Ag[cur][(wm + mi * 16 + fr) * 32 + ((fq * 8) ^ swz)]);
      au[mi] = *reinterpret_cast<const short8*>(
          &Au[cur][(wm + mi * 16 + fr) * 32 + ((fq * 8) ^ swz)]);
    }
#pragma unroll
    for (int nj = 0; nj < 4; ++nj) {
      bg[nj] = *reinterpret_cast<const short8*>(
          &Bg[cur][(wn + nj * 16 + fr) * 32 + ((fq * 8) ^ swz)]);
      bu[nj] = *reinterpret_cast<const short8*>(
          &Bu[cur][(wn + nj * 16 + fr) * 32 + ((fq * 8) ^ swz)]);
    }
#pragma unroll
    for (int mi = 0; mi < 2; ++mi)
#pragma unroll
      for (int nj = 0; nj < 4; ++nj) {
        accg[mi][nj] = MFMA16(ag[mi], bg[nj], accg[mi][nj], 0, 0, 0);
        accu[mi][nj] = MFMA16(au[mi], bu[nj], accu[mi][nj], 0, 0, 0);
      }
    __syncthreads();
  }
#pragma unroll
  for (int mi = 0; mi < 2; ++mi)
#pragma unroll
    for (int r = 0; r < 4; ++r) {
      int row = m0 + wm + mi * 16 + fq * 4 + r;
      if (row < c) {
#pragma unroll
        for (int nj = 0; nj < 4; ++nj) {
          float g = accg[mi][nj][r];
          float u = accu[mi][nj][r];
          float s = g / (1.f + expf(-g)) * u;
          a[(long)(o + row) * cF + n0 + wn + nj * 16 + fr] = f2bf(s);
        }
      }
    }
}

// ---------------------------------------------------------------------------
// t3p[ks] = a @ udT^T (split-K=4, fp32 partials).  [4][ROWS][256].
// LDS double-buffer + XOR-swizzled staging. 11 iters.
// grid = (16, 32, E): x = n(0..3) | ksp(0..3)<<2  -> ~1024 active blocks.
// ---------------------------------------------------------------------------
__global__ __launch_bounds__(256, 4) void k_t3(
    const unsigned short* __restrict__ a, const unsigned short* __restrict__ udT,
    float* __restrict__ t3p, const int* __restrict__ cnt,
    const int* __restrict__ off)
{
  __shared__ __align__(16) unsigned short As[2][64 * 64], Bs[2][64 * 64];
  const int e = blockIdx.z, c = cnt[e], o = off[e];
  const int m0 = blockIdx.y * 64;
  if (m0 >= c) return;
  const int n0 = (blockIdx.x & 3) * 64;
  const int ksp = blockIdx.x >> 2;                 // 0..3
  const int kbase = ksp * 704;
  const int tid = threadIdx.x;
  const int wid = tid >> 6, lane = tid & 63;
  const int sr8 = lane >> 3;
  const int scs = ((lane & 7) ^ sr8) * 8;          // pre-swizzled source col
  const int ra0 = o + min(m0 + wid * 16 + sr8, c - 1);
  const int ra1 = o + min(m0 + wid * 16 + 8 + sr8, c - 1);
  const unsigned short* gA0 = a + (long)ra0 * cF + kbase + scs;
  const unsigned short* gA1 = a + (long)ra1 * cF + kbase + scs;
  const unsigned short* gB  = udT + (long)e * 256 * cF +
      (long)(n0 + wid * 16 + sr8) * cF + kbase + scs;
  const int lofs = wid * 16 * 64;
  auto STAGE = [&](int k0, int buf) {
    gld16(gA0 + k0, &As[buf][lofs]);
    gld16(gA1 + k0, &As[buf][lofs + 8 * 64]);
    gld16(gB + k0, &Bs[buf][lofs]);
    gld16(gB + (long)8 * cF + k0, &Bs[buf][lofs + 8 * 64]);
  };
  const int wm = (wid >> 1) * 32, wn = (wid & 1) * 32;
  const int fr = lane & 15, fq = lane >> 4;
  const int swz = (fr & 7) * 8;                    // read-side XOR (shorts)
  float4v zf = {0.f, 0.f, 0.f, 0.f};
  float4v acc[2][2] = {{zf, zf}, {zf, zf}};
  STAGE(0, 0);
  __syncthreads();
  for (int t = 0; t < 11; ++t) {
    const int cur = t & 1;
    if (t < 10) STAGE((t + 1) * 64, cur ^ 1);
#pragma unroll
    for (int ks = 0; ks < 2; ++ks) {
      short8 af[2], bf[2];
#pragma unroll
      for (int mi = 0; mi < 2; ++mi)
        af[mi] = *reinterpret_cast<const short8*>(
            &As[cur][(wm + mi * 16 + fr) * 64 + ((ks * 32 + fq * 8) ^ swz)]);
#pragma unroll
      for (int nj = 0; nj < 2; ++nj)
        bf[nj] = *reinterpret_cast<const short8*>(
            &Bs[cur][(wn + nj * 16 + fr) * 64 + ((ks * 32 + fq * 8) ^ swz)]);
#pragma unroll
      for (int mi = 0; mi < 2; ++mi)
#pragma unroll
        for (int nj = 0; nj < 2; ++nj)
          acc[mi][nj] = MFMA16(af[mi], bf[nj], acc[mi][nj], 0, 0, 0);
    }
    __syncthreads();
  }
  float* dstbase = t3p + (long)ksp * ROWS * 256;
#pragma unroll
  for (int mi = 0; mi < 2; ++mi)
#pragma unroll
    for (int r = 0; r < 4; ++r) {
      int row = m0 + wm + mi * 16 + fq * 4 + r;
      if (row < c) {
        float* dst = dstbase + (long)(o + row) * 256 + n0 + wn;
#pragma unroll
        for (int nj = 0; nj < 2; ++nj)
          dst[nj * 16 + fr] = acc[mi][nj][r];
      }
    }
}

// ---------------------------------------------------------------------------
// t3b bf16 = sum of 4 fp32 t3p partials (pure streaming). grid = 512.
// ---------------------------------------------------------------------------
__global__ __launch_bounds__(256) void k_red(
    const float* __restrict__ t3p, unsigned short* __restrict__ t3b)
{
  const long psz = (long)ROWS * 256;
  long i = ((long)blockIdx.x * 256 + threadIdx.x) * 8;
  float4 s0 = *reinterpret_cast<const float4*>(t3p + i);
  float4 s1 = *reinterpret_cast<const float4*>(t3p + i + 4);
#pragma unroll
  for (int q = 1; q < 4; ++q) {
    float4 a0 = *reinterpret_cast<const float4*>(t3p + q * psz + i);
    float4 a1 = *reinterpret_cast<const float4*>(t3p + q * psz + i + 4);
    s0.x += a0.x; s0.y += a0.y; s0.z += a0.z; s0.w += a0.w;
    s1.x += a1.x; s1.y += a1.y; s1.z += a1.z; s1.w += a1.w;
  }
  store_bf8(t3b + i, s0, s1);
}

// ---------------------------------------------------------------------------
// y = t3b @ vd2t^T   [rows x 1024] bf16. K = 256.
// M-TILE 64: tile 64x64, acc[2][2], BK=32, dbuf + XOR swizzle (4-chunk).
// grid = (16, cT/64, E)
// ---------------------------------------------------------------------------
__global__ __launch_bounds__(256, 4) void k_y(
    const unsigned short* __restrict__ t3b, const unsigned short* __restrict__ vd2t,
    unsigned short* __restrict__ y, const int* __restrict__ cnt,
    const int* __restrict__ off)
{
  __shared__ __align__(16) unsigned short As[2][64 * 32], Bs[2][64 * 32];
  const int e = blockIdx.z, c = cnt[e], o = off[e];
  const int m0 = blockIdx.y * 64;
  if (m0 >= c) return;
  const int n0 = blockIdx.x * 64;
  const int tid = threadIdx.x;
  const int wid = tid >> 6, lane = tid & 63;
  const int sr16 = lane >> 2;
  const int scs = (((lane & 3) ^ (sr16 & 3)) * 8); // pre-swizzled source col
  const int ra = o + min(m0 + wid * 16 + sr16, c - 1);
  const unsigned short* gA = t3b + (long)ra * 256 + scs;
  const unsigned short* gB = vd2t + (long)e * cH * 256 + (long)(n0 + wid * 16 + sr16) * 256 + scs;
  const int lofs = wid * 16 * 32;
  auto STAGE = [&](int k0, int buf) {
    gld16(gA + k0, &As[buf][lofs]);
    gld16(gB + k0, &Bs[buf][lofs]);
  };
  const int wm = (wid >> 1) * 32, wn = (wid & 1) * 32;
  const int fr = lane & 15, fq = lane >> 4;
  const int swz = (fr & 3) * 8;                    // read-side XOR (shorts)
  float4v zf = {0.f, 0.f, 0.f, 0.f};
  float4v acc[2][2] = {{zf, zf}, {zf, zf}};
  STAGE(0, 0);
  __syncthreads();
  for (int t = 0; t < 8; ++t) {
    const int cur = t & 1;
    if (t < 7) STAGE((t + 1) * 32, cur ^ 1);
    short8 af[2], bf[2];
#pragma unroll
    for (int mi = 0; mi < 2; ++mi)
      af[mi] = *reinterpret_cast<const short8*>(
          &As[cur][(wm + mi * 16 + fr) * 32 + ((fq * 8) ^ swz)]);
#pragma unroll
    for (int nj = 0; nj < 2; ++nj)
      bf[nj] = *reinterpret_cast<const short8*>(
          &Bs[cur][(wn + nj * 16 + fr) * 32 + ((fq * 8) ^ swz)]);
#pragma unroll
    for (int mi = 0; mi < 2; ++mi)
#pragma unroll
      for (int nj = 0; nj < 2; ++nj)
        acc[mi][nj] = MFMA16(af[mi], bf[nj], acc[mi][nj], 0, 0, 0);
    __syncthreads();
  }
#pragma unroll
  for (int mi = 0; mi < 2; ++mi)
#pragma unroll
    for (int r = 0; r < 4; ++r) {
      int row = m0 + wm + mi * 16 + fq * 4 + r;
      if (row < c) {
#pragma unroll
        for (int nj = 0; nj < 2; ++nj)
          y[(long)(o + row) * cH + n0 + wn + nj * 16 + fr] = f2bf(acc[mi][nj][r]);
      }
    }
}

// ---------------------------------------------------------------------------
// out[t] = w0 * y[rowmap[2t]] + w1 * y[rowmap[2t+1]]   (pure write, no zero)
// ---------------------------------------------------------------------------
__global__ __launch_bounds__(256) void k_combine(
    const unsigned short* __restrict__ y, const float* __restrict__ wt,
    const int* __restrict__ rowmap, float* __restrict__ out)
{
  const int tid = threadIdx.x;
  const int t = blockIdx.x * 2 + (tid >> 7);
  const int h = (tid & 127) * 8;
  const int r0 = rowmap[2 * t], r1 = rowmap[2 * t + 1];
  const float w0 = wt[2 * t], w1 = wt[2 * t + 1];
  union { uint4 v; unsigned short s[8]; } ua, ub;
  ua.v = *reinterpret_cast<const uint4*>(y + (long)r0 * cH + h);
  ub.v = *reinterpret_cast<const uint4*>(y + (long)r1 * cH + h);
  float o[8];
#pragma unroll
  for (int i = 0; i < 8; ++i)
    o[i] = w0 * bf2f(ua.s[i]) + w1 * bf2f(ub.s[i]);
  float* dst = out + (long)t * cH + h;
  *reinterpret_cast<float4*>(dst)     = make_float4(o[0], o[1], o[2], o[3]);
  *reinterpret_cast<float4*>(dst + 4) = make_float4(o[4], o[5], o[6], o[7]);
}

// ---------------------------------------------------------------------------
extern "C" void kernel_launch(void* const* d_in, const int* in_sizes, int n_in,
                              void* d_out, int out_size, void* d_ws, size_t ws_size,
                              hipStream_t stream)
{
  const float* x  = (const float*)d_in[0];
  const float* gw = (const float*)d_in[1];
  const float* Ug = (const float*)d_in[2];
  const float* Cg = (const float*)d_in[3];
  const float* Vg = (const float*)d_in[4];
  const float* Uu = (const float*)d_in[5];
  const float* Cu = (const float*)d_in[6];
  const float* Vu = (const float*)d_in[7];
  const float* Ud = (const float*)d_in[8];
  const float* Cd = (const float*)d_in[9];
  const float* Vd = (const float*)d_in[10];
  float* out = (float*)d_out;

  // workspace layout (~83 MiB peak, with aliasing)
  char* w = (char*)d_ws;
  unsigned short* vgT = (unsigned short*)w;
  float*          t3p = (float*)w;
  unsigned short* t3b = (unsigned short*)(w + (long)4 * ROWS * 256 * 4);
  w += (long)cE * cF * 256 * 2;                                               // 11.53
  unsigned short* b1t = (unsigned short*)w;  w += (long)cE * 512 * 1024 * 2;  // 8.39
  unsigned short* vd2t = (unsigned short*)w; w += (long)cE * cH * 256 * 2;    // 4.19
  unsigned short* vuT = (unsigned short*)w;
  unsigned short* yb  = (unsigned short*)w;  w += (long)cE * cF * 256 * 2;    // 11.53
  unsigned short* udT = (unsigned short*)w;  w += (long)cE * 256 * cF * 2;    // 11.53
  unsigned short* VdT = (unsigned short*)w;  w += (long)cE * cH * 256 * 2;    // 4.19
  unsigned short* xb  = (unsigned short*)w;  w += (long)cT * cH * 2;          // 4.19
  unsigned short* CgT = (unsigned short*)w;  w += (long)cR * cR * 2;          // 0.13
  unsigned short* CuT = (unsigned short*)w;  w += (long)cR * cR * 2;          // 0.13
  unsigned short* t1  = (unsigned short*)w;  w += (long)ROWS * 512 * 2;       // 4.19
  unsigned short* ab  = (unsigned short*)w;  w += (long)ROWS * cF * 2;        // 23.07
  float* wt   = (float*)w; w += ROWS * 4;
  int* et     = (int*)w; w += ROWS * 4;
  int* rowmap = (int*)w; w += ROWS * 4;
  int* tok    = (int*)w; w += ROWS * 4;
  int* cnt = (int*)w; w += cE * 4;
  int* off = (int*)w; w += cE * 4;

  // L1: SMALL transposes (Cg/Cu/Vd) + gating + x->bf16
  k_prep1s<<<dim3(PREP1_BLOCKS), dim3(256), 0, stream>>>(
      Cg, CgT, Cu, CuT, Vd, VdT, x, gw, xb, et, wt);
  // L2: folds + lists + BIG transposes (Vg/Vu/Ud), co-scheduled
  k_prep2<<<dim3(PREP2_BLOCKS), dim3(256), 0, stream>>>(
      CgT, CuT, Ug, Uu, b1t, VdT, Cd, vd2t,
      Vg, vgT, Vu, vuT, Ud, udT, et, rowmap, tok, cnt, off);
  // L3: compact t1 GEMM (M=64, dbuf + swizzle)
  k_t1c<<<dim3(8, cT / 64, cE), dim3(256), 0, stream>>>(xb, b1t, t1, tok, cnt, off);
  // L4: a = silu(t1g @ Vg) * (t1u @ Vu)  (64x128 wide retile, acc 2x4)
  k_act<<<dim3(cF / 128, cT / 64, cE), dim3(256), 0, stream>>>(t1, vgT, vuT, ab, cnt, off);
  // L5: t3p = a @ Ud (split-K=4, dbuf + swizzle; aliases dead vgT+b1t)
  k_t3<<<dim3(16, cT / 64, cE), dim3(256), 0, stream>>>(ab, udT, t3p, cnt, off);
  // L6: t3b = bf16(sum of 4 partials)
  k_red<<<dim3(ROWS * 256 / (256 * 8)), dim3(256), 0, stream>>>(t3p, t3b);
  // L7: y = t3b @ Vd2 (M=64, dbuf + swizzle; aliases dead vuT)
  k_y<<<dim3(cH / 64, cT / 64, cE), dim3(256), 0, stream>>>(t3b, vd2t, yb, cnt, off);
  // L8: out = w0*y[r0] + w1*y[r1]
  k_combine<<<dim3(cT / 2), dim3(256), 0, stream>>>(yb, wt, rowmap, out);
}

// Round 13
// 261.845 us; speedup vs baseline: 1.0044x; 1.0044x over previous
//
#include <hip/hip_runtime.h>
#include <math.h>

constexpr int cE = 8;
constexpr int cH = 1024;
constexpr int cF = 2816;
constexpr int cR = 256;
constexpr int cT = 2048;
constexpr int ROWS = cT * 2;   // total routed (token, expert) rows = T*K
constexpr int LDA = 40;        // padded LDS row stride (foldm reg-staged kernel)

using short8  = __attribute__((ext_vector_type(8))) short;
using float4v = __attribute__((ext_vector_type(4))) float;
#define MFMA16 __builtin_amdgcn_mfma_f32_16x16x32_bf16

__device__ __forceinline__ unsigned short f2bf(float f) {
  union { float f; unsigned u; } v; v.f = f;
  unsigned r = v.u + 0x7fffu + ((v.u >> 16) & 1u);   // RNE
  return (unsigned short)(r >> 16);
}
__device__ __forceinline__ float bf2f(unsigned short s) {
  union { unsigned u; float f; } v; v.u = (unsigned)s << 16; return v.f;
}

// pack 8 fp32 -> 8 bf16, single 16B store
__device__ __forceinline__ void store_bf8(unsigned short* dst, float4 a, float4 b) {
  union { unsigned short u[8]; uint4 v; } t;
  t.u[0] = f2bf(a.x); t.u[1] = f2bf(a.y); t.u[2] = f2bf(a.z); t.u[3] = f2bf(a.w);
  t.u[4] = f2bf(b.x); t.u[5] = f2bf(b.y); t.u[6] = f2bf(b.z); t.u[7] = f2bf(b.w);
  *reinterpret_cast<uint4*>(dst) = t.v;
}

// async global->LDS, 16 B per lane. LDS dest = wave-uniform base + lane*16,
// global source address is per-lane (gather/swizzle-capable).
__device__ __forceinline__ void gld16(const unsigned short* g, unsigned short* l) {
  __builtin_amdgcn_global_load_lds(
      (const __attribute__((address_space(1))) void*)g,
      (__attribute__((address_space(3))) void*)l, 16, 0, 0);
}

// ---------------------------------------------------------------------------
// 64x64 transpose tile (fp32 -> bf16): in [P][Q] per batch -> out [Q][P].
// ---------------------------------------------------------------------------
__device__ __forceinline__ void tconv_tile64(
    const float* __restrict__ in, unsigned short* __restrict__ out,
    int P, int Q, int e, int bx, int by, int tid, float (*tile)[65])
{
  const long es = (long)P * Q;
  in += e * es; out += e * es;
  const int c0 = bx * 64, r0 = by * 64;
  const int r = tid >> 4, c4 = (tid & 15) * 4;
#pragma unroll
  for (int p = 0; p < 4; ++p) {
    float4 v = *reinterpret_cast<const float4*>(
        in + (long)(r0 + p * 16 + r) * Q + c0 + c4);
    tile[p * 16 + r][c4 + 0] = v.x; tile[p * 16 + r][c4 + 1] = v.y;
    tile[p * 16 + r][c4 + 2] = v.z; tile[p * 16 + r][c4 + 3] = v.w;
  }
  __syncthreads();
  const int cc = tid >> 4, rr4 = (tid & 15) * 4;
#pragma unroll
  for (int p = 0; p < 4; ++p) {
    ushort4 o;
    o.x = f2bf(tile[rr4 + 0][p * 16 + cc]);
    o.y = f2bf(tile[rr4 + 1][p * 16 + cc]);
    o.z = f2bf(tile[rr4 + 2][p * 16 + cc]);
    o.w = f2bf(tile[rr4 + 3][p * 16 + cc]);
    *reinterpret_cast<ushort4*>(out + (long)(c0 + p * 16 + cc) * P + r0 + rr4) = o;
  }
}

// ---------------------------------------------------------------------------
// LAUNCH 1: SMALL transposes (Cg/Cu/Vd, 544 tiles) + gating + x->bf16.
//  [0,16) Cg | [16,32) Cu | [32,544) Vd | [544,1056) gating
// ---------------------------------------------------------------------------
constexpr int P1_TCONV = 544;
constexpr int PREP1_BLOCKS = P1_TCONV + cT / 4;

__global__ __launch_bounds__(256) void k_prep1s(
    const float* __restrict__ Cg, unsigned short* __restrict__ CgT,
    const float* __restrict__ Cu, unsigned short* __restrict__ CuT,
    const float* __restrict__ Vd, unsigned short* __restrict__ VdT,
    const float* __restrict__ x, const float* __restrict__ gw,
    unsigned short* __restrict__ xb, int* __restrict__ et,
    float* __restrict__ wt)
{
  __shared__ float tile[64][65];
  int b = blockIdx.x;
  const int tid = threadIdx.x;
  if (b < P1_TCONV) {
    const float* in; unsigned short* out; int P, Q;
    if (b < 16)       { in = Cg; out = CgT; P = 256; Q = 256;  }
    else if (b < 32)  { b -= 16; in = Cu; out = CuT; P = 256; Q = 256;  }
    else              { b -= 32; in = Vd; out = VdT; P = 256; Q = 1024; }
    const int tpe = (P / 64) * (Q / 64);
    const int e = b / tpe, rem = b % tpe;
    const int bx = rem % (Q / 64), by = rem / (Q / 64);
    tconv_tile64(in, out, P, Q, e, bx, by, tid, tile);
    return;
  }
  // ---- gating path ----
  const int wid = tid >> 6, lane = tid & 63;
  const int t = (b - P1_TCONV) * 4 + wid;
  const float* xr = x + (long)t * cH + lane * 16;
  float4 v0 = *reinterpret_cast<const float4*>(xr);
  float4 v1 = *reinterpret_cast<const float4*>(xr + 4);
  float4 v2 = *reinterpret_cast<const float4*>(xr + 8);
  float4 v3 = *reinterpret_cast<const float4*>(xr + 12);
  store_bf8(xb + (long)t * cH + lane * 16, v0, v1);
  store_bf8(xb + (long)t * cH + lane * 16 + 8, v2, v3);
  float xv[16];
  *reinterpret_cast<float4*>(&xv[0])  = v0;
  *reinterpret_cast<float4*>(&xv[4])  = v1;
  *reinterpret_cast<float4*>(&xv[8])  = v2;
  *reinterpret_cast<float4*>(&xv[12]) = v3;
  const float* g = gw + (long)lane * 16 * cE;
  float l[cE];
#pragma unroll
  for (int e = 0; e < cE; ++e) l[e] = 0.f;
#pragma unroll
  for (int i = 0; i < 16; ++i) {
    float4 ga = *reinterpret_cast<const float4*>(g + i * cE);
    float4 gb = *reinterpret_cast<const float4*>(g + i * cE + 4);
    float xi = xv[i];
    l[0] += xi * ga.x; l[1] += xi * ga.y; l[2] += xi * ga.z; l[3] += xi * ga.w;
    l[4] += xi * gb.x; l[5] += xi * gb.y; l[6] += xi * gb.z; l[7] += xi * gb.w;
  }
#pragma unroll
  for (int m = 1; m < 64; m <<= 1)
#pragma unroll
    for (int e = 0; e < cE; ++e)
      l[e] += __shfl_xor(l[e], m, 64);
  if (lane == 0) {
    int i0 = 0; float m0 = l[0];
#pragma unroll
    for (int e = 1; e < cE; ++e) if (l[e] > m0) { m0 = l[e]; i0 = e; }
    int i1 = -1; float m1 = -1e30f;
#pragma unroll
    for (int e = 0; e < cE; ++e) if (e != i0 && l[e] > m1) { m1 = l[e]; i1 = e; }
    float w0 = 1.f / (1.f + expf(m1 - m0));
    et[t * 2 + 0] = i0;  et[t * 2 + 1] = i1;
    wt[t * 2 + 0] = w0;  wt[t * 2 + 1] = 1.f - w0;
  }
}

// ---------------------------------------------------------------------------
// MFMA fold body: D[m][n] = sum_k A[m][k] * B[n][k],  K = 256 fixed.
// tile 128x64, BK=32, register prefetch.
// ---------------------------------------------------------------------------
__device__ __forceinline__ void foldm_body(
    const unsigned short* __restrict__ A, const float* __restrict__ B,
    unsigned short* __restrict__ D, int ldd, int m0, int n0, int tid,
    unsigned short* As, unsigned short* Bs)
{
  const int sr = tid >> 2, sk = (tid & 3) * 8;
  const unsigned short* a0 = A + (long)(m0 + sr) * 256 + sk;
  const unsigned short* a1 = a0 + (long)64 * 256;
  const float* br = B + (long)(n0 + sr) * 256 + sk;
  uint4 rA0, rA1; float4 rB0, rB1;
  auto load_slice = [&](int k0) {
    rA0 = *reinterpret_cast<const uint4*>(a0 + k0);
    rA1 = *reinterpret_cast<const uint4*>(a1 + k0);
    rB0 = *reinterpret_cast<const float4*>(br + k0);
    rB1 = *reinterpret_cast<const float4*>(br + k0 + 4);
  };
  load_slice(0);
  const int wid = tid >> 6, lane = tid & 63;
  const int wm = (wid >> 1) * 64, wn = (wid & 1) * 32;
  const int fr = lane & 15, fq = lane >> 4;
  float4v zf = {0.f, 0.f, 0.f, 0.f};
  float4v acc[4][2];
#pragma unroll
  for (int i = 0; i < 4; ++i) { acc[i][0] = zf; acc[i][1] = zf; }
  for (int k0 = 0; k0 < 256; k0 += 32) {
    *reinterpret_cast<uint4*>(&As[sr * LDA + sk]) = rA0;
    *reinterpret_cast<uint4*>(&As[(sr + 64) * LDA + sk]) = rA1;
    store_bf8(&Bs[sr * LDA + sk], rB0, rB1);
    if (k0 + 32 < 256) load_slice(k0 + 32);
    __syncthreads();
    short8 af[4], bf[2];
#pragma unroll
    for (int mi = 0; mi < 4; ++mi)
      af[mi] = *reinterpret_cast<const short8*>(&As[(wm + mi * 16 + fr) * LDA + fq * 8]);
#pragma unroll
    for (int nj = 0; nj < 2; ++nj)
      bf[nj] = *reinterpret_cast<const short8*>(&Bs[(wn + nj * 16 + fr) * LDA + fq * 8]);
#pragma unroll
    for (int mi = 0; mi < 4; ++mi)
#pragma unroll
      for (int nj = 0; nj < 2; ++nj)
        acc[mi][nj] = MFMA16(af[mi], bf[nj], acc[mi][nj], 0, 0, 0);
    __syncthreads();
  }
#pragma unroll
  for (int mi = 0; mi < 4; ++mi)
#pragma unroll
    for (int r = 0; r < 4; ++r) {
      int m = m0 + wm + mi * 16 + fq * 4 + r;
#pragma unroll
      for (int nj = 0; nj < 2; ++nj)
        D[(long)m * ldd + n0 + wn + nj * 16 + fr] = f2bf(acc[mi][nj][r]);
    }
}

// ---------------------------------------------------------------------------
// LAUNCH 2: folds (768) + lists (1) + BIG transposes Vg/Vu/Ud as PAIRED
// tiles (4224 tiles -> 2112 blocks): per block, tile-1's global loads are
// issued before tile-0's store phase (reg-pipelined, single LDS buffer) --
// load latency hides under the store. R3-proven amortization mechanism.
//  [0,512) b1t folds | [512,768) vd2t folds | 768 lists |
//  [769,2881) big-transpose pairs
// ---------------------------------------------------------------------------
constexpr int PREP2_BLOCKS = 769 + (3 * 1408) / 2;
__global__ __launch_bounds__(256, 3) void k_prep2(
    const unsigned short* __restrict__ CgT, const unsigned short* __restrict__ CuT,
    const float* __restrict__ Ug, const float* __restrict__ Uu,
    unsigned short* __restrict__ b1t,
    const unsigned short* __restrict__ VdT, const float* __restrict__ Cd,
    unsigned short* __restrict__ vd2t,
    const float* __restrict__ Vg, unsigned short* __restrict__ vgT,
    const float* __restrict__ Vu, unsigned short* __restrict__ vuT,
    const float* __restrict__ Ud, unsigned short* __restrict__ udT,
    const int* __restrict__ et, int* __restrict__ rowmap,
    int* __restrict__ tok, int* __restrict__ cnt, int* __restrict__ off)
{
  __shared__ __align__(16) char smem[64 * 65 * 4];   // 16640 B union
  const int b = blockIdx.x;
  const int tid = threadIdx.x;
  if (b < 512) {
    unsigned short* As = (unsigned short*)smem;
    unsigned short* Bs = As + 128 * LDA;
    const int bx = b & 15, by = (b >> 4) & 1, z = b >> 5;
    const int sel = z >> 3, e = z & 7;
    const unsigned short* A = sel ? CuT : CgT;
    const float* B = (sel ? Uu : Ug) + (long)e * cH * cR;
    unsigned short* Dp = b1t + (long)e * 512 * 1024 + (long)sel * 256 * 1024;
    foldm_body(A, B, Dp, cH, by * 128, bx * 64, tid, As, Bs);
  } else if (b < 768) {
    unsigned short* As = (unsigned short*)smem;
    unsigned short* Bs = As + 128 * LDA;
    const int b2 = b - 512;
    const int bx = b2 & 3, by = (b2 >> 2) & 7, e = b2 >> 5;
    foldm_body(VdT + (long)e * cH * cR, Cd, vd2t + (long)e * cH * 256, cR,
               by * 128, bx * 64, tid, As, Bs);
  } else if (b == 768) {
    // ---- lists path (single block) ----
    int* sc_ = (int*)smem;
    int* sp_ = sc_ + cE;
    int* so_ = sc_ + 2 * cE;
    if (tid < cE) { sc_[tid] = 0; sp_[tid] = 0; }
    __syncthreads();
    for (int i = tid; i < ROWS; i += 256) atomicAdd(&sc_[et[i]], 1);
    __syncthreads();
    if (tid == 0) {
      int s = 0;
      for (int e = 0; e < cE; ++e) { so_[e] = s; s += sc_[e]; }
    }
    __syncthreads();
    for (int i = tid; i < ROWS; i += 256) {
      int e = et[i];
      int slot = atomicAdd(&sp_[e], 1);
      int cr = so_[e] + slot;
      rowmap[i] = cr;
      tok[cr] = i >> 1;
    }
    if (tid < cE) { cnt[tid] = sc_[tid]; off[tid] = so_[tid]; }
  } else {
    // ---- big transpose path: 2 tiles per block, reg-pipelined ----
    float (*tile)[65] = reinterpret_cast<float(*)[65]>(smem);
    const int t0 = (b - 769) * 2;
    auto decode = [&](int t, const float*& in, unsigned short*& out,
                      int& P, int& Q, int& bx, int& by) {
      int e;
      if (t < 1408)       { in = Vg; out = vgT; P = 256;  Q = 2816; }
      else if (t < 2816)  { t -= 1408; in = Vu; out = vuT; P = 256;  Q = 2816; }
      else                { t -= 2816; in = Ud; out = udT; P = 2816; Q = 256;  }
      const int tpe = (P / 64) * (Q / 64);
      e = t / tpe; const int rem = t % tpe;
      bx = rem % (Q / 64); by = rem / (Q / 64);
      in  += (long)e * P * Q;
      out += (long)e * P * Q;
    };
    auto tload = [&](const float* in, int Q, int bx, int by, float4* v) {
      const float* p = in + (long)(by * 64 + (tid >> 4)) * Q + bx * 64 + (tid & 15) * 4;
#pragma unroll
      for (int i = 0; i < 4; ++i)
        v[i] = *reinterpret_cast<const float4*>(p + (long)i * 16 * Q);
    };
    auto twrite = [&](const float4* v) {
      const int r = tid >> 4, c4 = (tid & 15) * 4;
#pragma unroll
      for (int i = 0; i < 4; ++i) {
        tile[i * 16 + r][c4 + 0] = v[i].x; tile[i * 16 + r][c4 + 1] = v[i].y;
        tile[i * 16 + r][c4 + 2] = v[i].z; tile[i * 16 + r][c4 + 3] = v[i].w;
      }
    };
    auto tstore = [&](unsigned short* out, int P, int bx, int by) {
      const int cc = tid >> 4, rr4 = (tid & 15) * 4;
#pragma unroll
      for (int p = 0; p < 4; ++p) {
        ushort4 o;
        o.x = f2bf(tile[rr4 + 0][p * 16 + cc]);
        o.y = f2bf(tile[rr4 + 1][p * 16 + cc]);
        o.z = f2bf(tile[rr4 + 2][p * 16 + cc]);
        o.w = f2bf(tile[rr4 + 3][p * 16 + cc]);
        *reinterpret_cast<ushort4*>(
            out + (long)(bx * 64 + p * 16 + cc) * P + by * 64 + rr4) = o;
      }
    };
    const float *in0, *in1; unsigned short *out0, *out1;
    int P0, Q0, bx0, by0, P1, Q1, bx1, by1;
    decode(t0,     in0, out0, P0, Q0, bx0, by0);
    decode(t0 + 1, in1, out1, P1, Q1, bx1, by1);
    float4 v0[4], v1[4];
    tload(in0, Q0, bx0, by0, v0);
    twrite(v0);
    __syncthreads();
    tload(in1, Q1, bx1, by1, v1);   // issue loads; overlap with store below
    tstore(out0, P0, bx0, by0);
    __syncthreads();                // all reads of tile done before overwrite
    twrite(v1);                     // waits only on v1 loads
    __syncthreads();
    tstore(out1, P1, bx1, by1);
  }
}

// ---------------------------------------------------------------------------
// COMPACT t1 GEMM: t1[o+row] = xb[tok[o+row]] @ b1t[e]^T   (K=1024, N=512)
// M-TILE 64: tile 64x64, BK=64, acc[2][2], dbuf + XOR swizzle (8-chunk).
// grid = (8, cT/64, E), early-return past cnt[e].
// ---------------------------------------------------------------------------
__global__ __launch_bounds__(256, 4) void k_t1c(
    const unsigned short* __restrict__ xb, const unsigned short* __restrict__ b1t,
    unsigned short* __restrict__ t1, const int* __restrict__ tok,
    const int* __restrict__ cnt, const int* __restrict__ off)
{
  __shared__ __align__(16) unsigned short As[2][64 * 64], Bs[2][64 * 64];
  const int e = blockIdx.z, c = cnt[e], o = off[e];
  const int m0 = blockIdx.y * 64;
  if (m0 >= c) return;
  const int n0 = blockIdx.x * 64;
  const int tid = threadIdx.x;
  const int wid = tid >> 6, lane = tid & 63;
  const int sr8 = lane >> 3;
  const int scs = ((lane & 7) ^ sr8) * 8;          // pre-swizzled source col
  const unsigned short* gA[2];
#pragma unroll
  for (int j = 0; j < 2; ++j) {
    int row = min(m0 + wid * 16 + j * 8 + sr8, c - 1);
    gA[j] = xb + (long)tok[o + row] * cH + scs;
  }
  const unsigned short* gB = b1t + (long)e * 512 * 1024 +
      (long)(n0 + wid * 16 + sr8) * 1024 + scs;
  const int lofs = wid * 16 * 64;
  auto STAGE = [&](int k0, int buf) {
    gld16(gA[0] + k0, &As[buf][lofs]);
    gld16(gA[1] + k0, &As[buf][lofs + 8 * 64]);
    gld16(gB + k0, &Bs[buf][lofs]);
    gld16(gB + (long)8 * 1024 + k0, &Bs[buf][lofs + 8 * 64]);
  };
  const int wm = (wid >> 1) * 32, wn = (wid & 1) * 32;
  const int fr = lane & 15, fq = lane >> 4;
  const int swz = (fr & 7) * 8;                    // read-side XOR (shorts)
  float4v zf = {0.f, 0.f, 0.f, 0.f};
  float4v acc[2][2] = {{zf, zf}, {zf, zf}};
  STAGE(0, 0);
  __syncthreads();
  for (int t = 0; t < 16; ++t) {
    const int cur = t & 1;
    if (t < 15) STAGE((t + 1) * 64, cur ^ 1);
#pragma unroll
    for (int ks = 0; ks < 2; ++ks) {
      short8 af[2], bf[2];
#pragma unroll
      for (int mi = 0; mi < 2; ++mi)
        af[mi] = *reinterpret_cast<const short8*>(
            &As[cur][(wm + mi * 16 + fr) * 64 + ((ks * 32 + fq * 8) ^ swz)]);
#pragma unroll
      for (int nj = 0; nj < 2; ++nj)
        bf[nj] = *reinterpret_cast<const short8*>(
            &Bs[cur][(wn + nj * 16 + fr) * 64 + ((ks * 32 + fq * 8) ^ swz)]);
#pragma unroll
      for (int mi = 0; mi < 2; ++mi)
#pragma unroll
        for (int nj = 0; nj < 2; ++nj)
          acc[mi][nj] = MFMA16(af[mi], bf[nj], acc[mi][nj], 0, 0, 0);
    }
    __syncthreads();
  }
#pragma unroll
  for (int mi = 0; mi < 2; ++mi)
#pragma unroll
    for (int r = 0; r < 4; ++r) {
      int row = m0 + wm + mi * 16 + fq * 4 + r;
      if (row < c) {
#pragma unroll
        for (int nj = 0; nj < 2; ++nj)
          t1[(long)(o + row) * 512 + n0 + wn + nj * 16 + fr] = f2bf(acc[mi][nj][r]);
      }
    }
}

// ---------------------------------------------------------------------------
// dual GEMM: a = silu(t1g @ vgT^T) * (t1u @ vuT^T)  [rows x F], K=256
// M-TILE 64 (R9-proven best): tile 64x64, acc[2][2] x2 dtypes, LDS 32 KB,
// BK=32, dbuf + XOR swizzle (4-chunk). grid = (44, cT/64, E)
// ---------------------------------------------------------------------------
__global__ __launch_bounds__(256, 4) void k_act(
    const unsigned short* __restrict__ t1,
    const unsigned short* __restrict__ vgT, const unsigned short* __restrict__ vuT,
    unsigned short* __restrict__ a, const int* __restrict__ cnt,
    const int* __restrict__ off)
{
  __shared__ __align__(16) unsigned short Ag[2][64 * 32], Au[2][64 * 32];
  __shared__ __align__(16) unsigned short Bg[2][64 * 32], Bu[2][64 * 32];
  const int e = blockIdx.z, c = cnt[e], o = off[e];
  const int m0 = blockIdx.y * 64;
  if (m0 >= c) return;
  const int n0 = blockIdx.x * 64;
  const int tid = threadIdx.x;
  const int wid = tid >> 6, lane = tid & 63;
  const int sr16 = lane >> 2;
  const int scs = (((lane & 3) ^ (sr16 & 3)) * 8); // pre-swizzled source col
  const int ra = o + min(m0 + wid * 16 + sr16, c - 1);
  const unsigned short* gAg = t1 + (long)ra * 512 + scs;
  const unsigned short* gBg = vgT + (long)e * cF * 256 + (long)(n0 + wid * 16 + sr16) * 256 + scs;
  const unsigned short* gBu = vuT + (long)e * cF * 256 + (long)(n0 + wid * 16 + sr16) * 256 + scs;
  const int lofs = wid * 16 * 32;
  auto STAGE = [&](int k0, int buf) {
    gld16(gAg + k0, &Ag[buf][lofs]);
    gld16(gAg + 256 + k0, &Au[buf][lofs]);
    gld16(gBg + k0, &Bg[buf][lofs]);
    gld16(gBu + k0, &Bu[buf][lofs]);
  };
  const int wm = (wid >> 1) * 32, wn = (wid & 1) * 32;
  const int fr = lane & 15, fq = lane >> 4;
  const int swz = (fr & 3) * 8;                    // read-side XOR (shorts)
  float4v zf = {0.f, 0.f, 0.f, 0.f};
  float4v accg[2][2] = {{zf, zf}, {zf, zf}};
  float4v accu[2][2] = {{zf, zf}, {zf, zf}};
  STAGE(0, 0);
  __syncthreads();
  for (int t = 0; t < 8; ++t) {
    const int cur = t & 1;
    if (t < 7) STAGE((t + 1) * 32, cur ^ 1);
    short8 ag[2], au[2], bg[2], bu[2];
#pragma unroll
    for (int mi = 0; mi < 2; ++mi) {
      ag[mi] = *reinterpret_cast<const short8*>(
          &Ag[cur][(wm + mi * 16 + fr) * 32 + ((fq * 8) ^ swz)]);
      au[mi] = *reinterpret_cast<const short8*>(
          &Au[cur][(wm + mi * 16 + fr) * 32 + ((fq * 8) ^ swz)]);
    }
#pragma unroll
    for (int nj = 0; nj < 2; ++nj) {
      bg[nj] = *reinterpret_cast<const short8*>(
          &Bg[cur][(wn + nj * 16 + fr) * 32 + ((fq * 8) ^ swz)]);
      bu[nj] = *reinterpret_cast<const short8*>(
          &Bu[cur][(wn + nj * 16 + fr) * 32 + ((fq * 8) ^ swz)]);
    }
#pragma unroll
    for (int mi = 0; mi < 2; ++mi)
#pragma unroll
      for (int nj = 0; nj < 2; ++nj) {
        accg[mi][nj] = MFMA16(ag[mi], bg[nj], accg[mi][nj], 0, 0, 0);
        accu[mi][nj] = MFMA16(au[mi], bu[nj], accu[mi][nj], 0, 0, 0);
      }
    __syncthreads();
  }
#pragma unroll
  for (int mi = 0; mi < 2; ++mi)
#pragma unroll
    for (int r = 0; r < 4; ++r) {
      int row = m0 + wm + mi * 16 + fq * 4 + r;
      if (row < c) {
#pragma unroll
        for (int nj = 0; nj < 2; ++nj) {
          float g = accg[mi][nj][r];
          float u = accu[mi][nj][r];
          float s = g / (1.f + expf(-g)) * u;
          a[(long)(o + row) * cF + n0 + wn + nj * 16 + fr] = f2bf(s);
        }
      }
    }
}

// ---------------------------------------------------------------------------
// t3p[ks] = a @ udT^T (split-K=4, fp32 partials).  [4][ROWS][256].
// LDS double-buffer + XOR-swizzled staging. 11 iters.
// grid = (16, 32, E): x = n(0..3) | ksp(0..3)<<2  -> ~1024 active blocks.
// ---------------------------------------------------------------------------
__global__ __launch_bounds__(256, 4) void k_t3(
    const unsigned short* __restrict__ a, const unsigned short* __restrict__ udT,
    float* __restrict__ t3p, const int* __restrict__ cnt,
    const int* __restrict__ off)
{
  __shared__ __align__(16) unsigned short As[2][64 * 64], Bs[2][64 * 64];
  const int e = blockIdx.z, c = cnt[e], o = off[e];
  const int m0 = blockIdx.y * 64;
  if (m0 >= c) return;
  const int n0 = (blockIdx.x & 3) * 64;
  const int ksp = blockIdx.x >> 2;                 // 0..3
  const int kbase = ksp * 704;
  const int tid = threadIdx.x;
  const int wid = tid >> 6, lane = tid & 63;
  const int sr8 = lane >> 3;
  const int scs = ((lane & 7) ^ sr8) * 8;          // pre-swizzled source col
  const int ra0 = o + min(m0 + wid * 16 + sr8, c - 1);
  const int ra1 = o + min(m0 + wid * 16 + 8 + sr8, c - 1);
  const unsigned short* gA0 = a + (long)ra0 * cF + kbase + scs;
  const unsigned short* gA1 = a + (long)ra1 * cF + kbase + scs;
  const unsigned short* gB  = udT + (long)e * 256 * cF +
      (long)(n0 + wid * 16 + sr8) * cF + kbase + scs;
  const int lofs = wid * 16 * 64;
  auto STAGE = [&](int k0, int buf) {
    gld16(gA0 + k0, &As[buf][lofs]);
    gld16(gA1 + k0, &As[buf][lofs + 8 * 64]);
    gld16(gB + k0, &Bs[buf][lofs]);
    gld16(gB + (long)8 * cF + k0, &Bs[buf][lofs + 8 * 64]);
  };
  const int wm = (wid >> 1) * 32, wn = (wid & 1) * 32;
  const int fr = lane & 15, fq = lane >> 4;
  const int swz = (fr & 7) * 8;                    // read-side XOR (shorts)
  float4v zf = {0.f, 0.f, 0.f, 0.f};
  float4v acc[2][2] = {{zf, zf}, {zf, zf}};
  STAGE(0, 0);
  __syncthreads();
  for (int t = 0; t < 11; ++t) {
    const int cur = t & 1;
    if (t < 10) STAGE((t + 1) * 64, cur ^ 1);
#pragma unroll
    for (int ks = 0; ks < 2; ++ks) {
      short8 af[2], bf[2];
#pragma unroll
      for (int mi = 0; mi < 2; ++mi)
        af[mi] = *reinterpret_cast<const short8*>(
            &As[cur][(wm + mi * 16 + fr) * 64 + ((ks * 32 + fq * 8) ^ swz)]);
#pragma unroll
      for (int nj = 0; nj < 2; ++nj)
        bf[nj] = *reinterpret_cast<const short8*>(
            &Bs[cur][(wn + nj * 16 + fr) * 64 + ((ks * 32 + fq * 8) ^ swz)]);
#pragma unroll
      for (int mi = 0; mi < 2; ++mi)
#pragma unroll
        for (int nj = 0; nj < 2; ++nj)
          acc[mi][nj] = MFMA16(af[mi], bf[nj], acc[mi][nj], 0, 0, 0);
    }
    __syncthreads();
  }
  float* dstbase = t3p + (long)ksp * ROWS * 256;
#pragma unroll
  for (int mi = 0; mi < 2; ++mi)
#pragma unroll
    for (int r = 0; r < 4; ++r) {
      int row = m0 + wm + mi * 16 + fq * 4 + r;
      if (row < c) {
        float* dst = dstbase + (long)(o + row) * 256 + n0 + wn;
#pragma unroll
        for (int nj = 0; nj < 2; ++nj)
          dst[nj * 16 + fr] = acc[mi][nj][r];
      }
    }
}

// ---------------------------------------------------------------------------
// t3b bf16 = sum of 4 fp32 t3p partials (pure streaming). grid = 512.
// ---------------------------------------------------------------------------
__global__ __launch_bounds__(256) void k_red(
    const float* __restrict__ t3p, unsigned short* __restrict__ t3b)
{
  const long psz = (long)ROWS * 256;
  long i = ((long)blockIdx.x * 256 + threadIdx.x) * 8;
  float4 s0 = *reinterpret_cast<const float4*>(t3p + i);
  float4 s1 = *reinterpret_cast<const float4*>(t3p + i + 4);
#pragma unroll
  for (int q = 1; q < 4; ++q) {
    float4 a0 = *reinterpret_cast<const float4*>(t3p + q * psz + i);
    float4 a1 = *reinterpret_cast<const float4*>(t3p + q * psz + i + 4);
    s0.x += a0.x; s0.y += a0.y; s0.z += a0.z; s0.w += a0.w;
    s1.x += a1.x; s1.y += a1.y; s1.z += a1.z; s1.w += a1.w;
  }
  store_bf8(t3b + i, s0, s1);
}

// ---------------------------------------------------------------------------
// y = t3b @ vd2t^T   [rows x 1024] bf16. K = 256.
// M-TILE 64: tile 64x64, acc[2][2], BK=32, dbuf + XOR swizzle (4-chunk).
// grid = (16, cT/64, E)
// ---------------------------------------------------------------------------
__global__ __launch_bounds__(256, 4) void k_y(
    const unsigned short* __restrict__ t3b, const unsigned short* __restrict__ vd2t,
    unsigned short* __restrict__ y, const int* __restrict__ cnt,
    const int* __restrict__ off)
{
  __shared__ __align__(16) unsigned short As[2][64 * 32], Bs[2][64 * 32];
  const int e = blockIdx.z, c = cnt[e], o = off[e];
  const int m0 = blockIdx.y * 64;
  if (m0 >= c) return;
  const int n0 = blockIdx.x * 64;
  const int tid = threadIdx.x;
  const int wid = tid >> 6, lane = tid & 63;
  const int sr16 = lane >> 2;
  const int scs = (((lane & 3) ^ (sr16 & 3)) * 8); // pre-swizzled source col
  const int ra = o + min(m0 + wid * 16 + sr16, c - 1);
  const unsigned short* gA = t3b + (long)ra * 256 + scs;
  const unsigned short* gB = vd2t + (long)e * cH * 256 + (long)(n0 + wid * 16 + sr16) * 256 + scs;
  const int lofs = wid * 16 * 32;
  auto STAGE = [&](int k0, int buf) {
    gld16(gA + k0, &As[buf][lofs]);
    gld16(gB + k0, &Bs[buf][lofs]);
  };
  const int wm = (wid >> 1) * 32, wn = (wid & 1) * 32;
  const int fr = lane & 15, fq = lane >> 4;
  const int swz = (fr & 3) * 8;                    // read-side XOR (shorts)
  float4v zf = {0.f, 0.f, 0.f, 0.f};
  float4v acc[2][2] = {{zf, zf}, {zf, zf}};
  STAGE(0, 0);
  __syncthreads();
  for (int t = 0; t < 8; ++t) {
    const int cur = t & 1;
    if (t < 7) STAGE((t + 1) * 32, cur ^ 1);
    short8 af[2], bf[2];
#pragma unroll
    for (int mi = 0; mi < 2; ++mi)
      af[mi] = *reinterpret_cast<const short8*>(
          &As[cur][(wm + mi * 16 + fr) * 32 + ((fq * 8) ^ swz)]);
#pragma unroll
    for (int nj = 0; nj < 2; ++nj)
      bf[nj] = *reinterpret_cast<const short8*>(
          &Bs[cur][(wn + nj * 16 + fr) * 32 + ((fq * 8) ^ swz)]);
#pragma unroll
    for (int mi = 0; mi < 2; ++mi)
#pragma unroll
      for (int nj = 0; nj < 2; ++nj)
        acc[mi][nj] = MFMA16(af[mi], bf[nj], acc[mi][nj], 0, 0, 0);
    __syncthreads();
  }
#pragma unroll
  for (int mi = 0; mi < 2; ++mi)
#pragma unroll
    for (int r = 0; r < 4; ++r) {
      int row = m0 + wm + mi * 16 + fq * 4 + r;
      if (row < c) {
#pragma unroll
        for (int nj = 0; nj < 2; ++nj)
          y[(long)(o + row) * cH + n0 + wn + nj * 16 + fr] = f2bf(acc[mi][nj][r]);
      }
    }
}

// ---------------------------------------------------------------------------
// out[t] = w0 * y[rowmap[2t]] + w1 * y[rowmap[2t+1]]   (pure write, no zero)
// ---------------------------------------------------------------------------
__global__ __launch_bounds__(256) void k_combine(
    const unsigned short* __restrict__ y, const float* __restrict__ wt,
    const int* __restrict__ rowmap, float* __restrict__ out)
{
  const int tid = threadIdx.x;
  const int t = blockIdx.x * 2 + (tid >> 7);
  const int h = (tid & 127) * 8;
  const int r0 = rowmap[2 * t], r1 = rowmap[2 * t + 1];
  const float w0 = wt[2 * t], w1 = wt[2 * t + 1];
  union { uint4 v; unsigned short s[8]; } ua, ub;
  ua.v = *reinterpret_cast<const uint4*>(y + (long)r0 * cH + h);
  ub.v = *reinterpret_cast<const uint4*>(y + (long)r1 * cH + h);
  float o[8];
#pragma unroll
  for (int i = 0; i < 8; ++i)
    o[i] = w0 * bf2f(ua.s[i]) + w1 * bf2f(ub.s[i]);
  float* dst = out + (long)t * cH + h;
  *reinterpret_cast<float4*>(dst)     = make_float4(o[0], o[1], o[2], o[3]);
  *reinterpret_cast<float4*>(dst + 4) = make_float4(o[4], o[5], o[6], o[7]);
}

// ---------------------------------------------------------------------------
extern "C" void kernel_launch(void* const* d_in, const int* in_sizes, int n_in,
                              void* d_out, int out_size, void* d_ws, size_t ws_size,
                              hipStream_t stream)
{
  const float* x  = (const float*)d_in[0];
  const float* gw = (const float*)d_in[1];
  const float* Ug = (const float*)d_in[2];
  const float* Cg = (const float*)d_in[3];
  const float* Vg = (const float*)d_in[4];
  const float* Uu = (const float*)d_in[5];
  const float* Cu = (const float*)d_in[6];
  const float* Vu = (const float*)d_in[7];
  const float* Ud = (const float*)d_in[8];
  const float* Cd = (const float*)d_in[9];
  const float* Vd = (const float*)d_in[10];
  float* out = (float*)d_out;

  // workspace layout (~83 MiB peak, with aliasing)
  char* w = (char*)d_ws;
  unsigned short* vgT = (unsigned short*)w;
  float*          t3p = (float*)w;
  unsigned short* t3b = (unsigned short*)(w + (long)4 * ROWS * 256 * 4);
  w += (long)cE * cF * 256 * 2;                                               // 11.53
  unsigned short* b1t = (unsigned short*)w;  w += (long)cE * 512 * 1024 * 2;  // 8.39
  unsigned short* vd2t = (unsigned short*)w; w += (long)cE * cH * 256 * 2;    // 4.19
  unsigned short* vuT = (unsigned short*)w;
  unsigned short* yb  = (unsigned short*)w;  w += (long)cE * cF * 256 * 2;    // 11.53
  unsigned short* udT = (unsigned short*)w;  w += (long)cE * 256 * cF * 2;    // 11.53
  unsigned short* VdT = (unsigned short*)w;  w += (long)cE * cH * 256 * 2;    // 4.19
  unsigned short* xb  = (unsigned short*)w;  w += (long)cT * cH * 2;          // 4.19
  unsigned short* CgT = (unsigned short*)w;  w += (long)cR * cR * 2;          // 0.13
  unsigned short* CuT = (unsigned short*)w;  w += (long)cR * cR * 2;          // 0.13
  unsigned short* t1  = (unsigned short*)w;  w += (long)ROWS * 512 * 2;       // 4.19
  unsigned short* ab  = (unsigned short*)w;  w += (long)ROWS * cF * 2;        // 23.07
  float* wt   = (float*)w; w += ROWS * 4;
  int* et     = (int*)w; w += ROWS * 4;
  int* rowmap = (int*)w; w += ROWS * 4;
  int* tok    = (int*)w; w += ROWS * 4;
  int* cnt = (int*)w; w += cE * 4;
  int* off = (int*)w; w += cE * 4;

  // L1: SMALL transposes (Cg/Cu/Vd) + gating + x->bf16
  k_prep1s<<<dim3(PREP1_BLOCKS), dim3(256), 0, stream>>>(
      Cg, CgT, Cu, CuT, Vd, VdT, x, gw, xb, et, wt);
  // L2: folds + lists + BIG transposes (paired, reg-pipelined), co-scheduled
  k_prep2<<<dim3(PREP2_BLOCKS), dim3(256), 0, stream>>>(
      CgT, CuT, Ug, Uu, b1t, VdT, Cd, vd2t,
      Vg, vgT, Vu, vuT, Ud, udT, et, rowmap, tok, cnt, off);
  // L3: compact t1 GEMM (M=64, dbuf + swizzle)
  k_t1c<<<dim3(8, cT / 64, cE), dim3(256), 0, stream>>>(xb, b1t, t1, tok, cnt, off);
  // L4: a = silu(t1g @ Vg) * (t1u @ Vu)  (R9-proven M=64 config)
  k_act<<<dim3(cF / 64, cT / 64, cE), dim3(256), 0, stream>>>(t1, vgT, vuT, ab, cnt, off);
  // L5: t3p = a @ Ud (split-K=4, dbuf + swizzle; aliases dead vgT+b1t)
  k_t3<<<dim3(16, cT / 64, cE), dim3(256), 0, stream>>>(ab, udT, t3p, cnt, off);
  // L6: t3b = bf16(sum of 4 partials)
  k_red<<<dim3(ROWS * 256 / (256 * 8)), dim3(256), 0, stream>>>(t3p, t3b);
  // L7: y = t3b @ Vd2 (M=64, dbuf + swizzle; aliases dead vuT)
  k_y<<<dim3(cH / 64, cT / 64, cE), dim3(256), 0, stream>>>(t3b, vd2t, yb, cnt, off);
  // L8: out = w0*y[r0] + w1*y[r1]
  k_combine<<<dim3(cT / 2), dim3(256), 0, stream>>>(yb, wt, rowmap, out);
}